// Round 1
// baseline (532.240 us; speedup 1.0000x reference)
//
#include <hip/hip_runtime.h>
#include <hip/hip_bf16.h>
#include <cstdint>

// ---------- types ----------
typedef __bf16 bf16x8 __attribute__((ext_vector_type(8)));
typedef float  f32x4  __attribute__((ext_vector_type(4)));

typedef __attribute__((address_space(3))) void lds_void;
typedef const __attribute__((address_space(1))) void gbl_cvoid;

#define GLOAD_LDS16(g, l) \
    __builtin_amdgcn_global_load_lds((gbl_cvoid*)(g), (lds_void*)(l), 16, 0, 0)

// Problem constants
static constexpr int IN   = 4096;
static constexpr int OUT  = 4096;
static constexpr int RANK = 256;
static constexpr int M_ROWS = 4 * 2048;  // B*S = 8192

// ---------- device helpers ----------
__device__ __forceinline__ void cast8(const float* __restrict__ in,
                                      __bf16* __restrict__ out, int t) {
    const float4* p = (const float4*)in + (size_t)t * 2;
    float4 v0 = p[0], v1 = p[1];
    bf16x8 o;
    o[0] = (__bf16)v0.x; o[1] = (__bf16)v0.y; o[2] = (__bf16)v0.z; o[3] = (__bf16)v0.w;
    o[4] = (__bf16)v1.x; o[5] = (__bf16)v1.y; o[6] = (__bf16)v1.z; o[7] = (__bf16)v1.w;
    ((bf16x8*)out)[t] = o;
}

// ---------- kernel 1: prep = cast B (blocks 0..511) + make AdT (blocks 512..767) ----
__global__ __launch_bounds__(256) void prep(
    const float* __restrict__ Bm, __bf16* __restrict__ Bbf,
    const float* __restrict__ A,  const float* __restrict__ d,
    __bf16* __restrict__ AdT)
{
    __shared__ float tile[64][65];
    const int blk = blockIdx.x;
    const int t   = threadIdx.x;

    if (blk < 512) {                     // cast B: 1,048,576 elems / 8
        cast8(Bm, Bbf, blk * 256 + t);
        return;
    }
    const int ab = blk - 512;            // 0..255
    const int i0 = (ab & 63) * 64;
    const int r0 = (ab >> 6) * 64;
    const int cl = t & 63;
    const int rw = t >> 6;

#pragma unroll
    for (int it = 0; it < 16; ++it) {
        int rl = it * 4 + rw;
        tile[rl][cl] = A[(size_t)(r0 + rl) * IN + i0 + cl];
    }
    __syncthreads();
    float dv = d[r0 + cl];
#pragma unroll
    for (int it = 0; it < 16; ++it) {
        int il = it * 4 + rw;
        AdT[(size_t)(i0 + il) * RANK + r0 + cl] = (__bf16)(tile[cl][il] * dv);
    }
}

// ---------- kernel 2: fused Weff-GEMM (blocks 0..1023) + cast x (rest) ----------
// Weff[o][i] = bf16( W[o][i] + sum_r Bw[o][r]*AdT[i][r] )  (128x128 tile, verified)
__global__ __launch_bounds__(256) void weff_cast(
    const __bf16* __restrict__ Bw,   // [OUT, RANK] bf16
    const __bf16* __restrict__ AdT,  // [IN,  RANK] bf16
    const float*  __restrict__ W,    // [OUT, IN] fp32
    __bf16* __restrict__ Weff,       // [OUT, IN] bf16
    const float*  __restrict__ x,    // [8192, 4096] fp32
    __bf16* __restrict__ x_bf)       // [8192, 4096] bf16
{
    __shared__ __bf16 sA[128 * 64];
    __shared__ __bf16 sB[128 * 64];

    const int blk = blockIdx.x;
    const int t   = threadIdx.x;

    if (blk >= 1024) {                   // cast x: 33,554,432 elems / 8
        cast8(x, x_bf, (blk - 1024) * 256 + t);
        return;
    }

    constexpr int K = RANK;   // 256
    const int wave = t >> 6;
    const int lane = t & 63;
    const int quad = lane >> 4;
    const int l16  = lane & 15;
    const int m0 = (blk >> 5) * 128;   // o
    const int n0 = (blk & 31) * 128;   // i
    const int wm = (wave >> 1) * 64;
    const int wn = (wave & 1) * 64;
    const int xr = l16 & 7;

    f32x4 acc[4][4] = {};

    for (int kt = 0; kt < K; kt += 64) {
#pragma unroll
        for (int j = 0; j < 4; ++j) {
            int ci  = j * 256 + t;
            int row = ci >> 3;
            int kc  = (ci & 7) ^ (row & 7);
            GLOAD_LDS16(Bw  + (size_t)(m0 + row) * K + kt + kc * 8, sA + ci * 8);
        }
#pragma unroll
        for (int j = 0; j < 4; ++j) {
            int ci  = j * 256 + t;
            int row = ci >> 3;
            int kc  = (ci & 7) ^ (row & 7);
            GLOAD_LDS16(AdT + (size_t)(n0 + row) * K + kt + kc * 8, sB + ci * 8);
        }
        __syncthreads();

#pragma unroll
        for (int kk = 0; kk < 64; kk += 32) {
            const int kb = kk >> 3;
            bf16x8 a[4], b[4];
#pragma unroll
            for (int mi = 0; mi < 4; ++mi)
                a[mi] = *(const bf16x8*)(sA + (wm + mi * 16 + l16) * 64 + (((kb + quad) ^ xr) << 3));
#pragma unroll
            for (int ni = 0; ni < 4; ++ni)
                b[ni] = *(const bf16x8*)(sB + (wn + ni * 16 + l16) * 64 + (((kb + quad) ^ xr) << 3));
#pragma unroll
            for (int mi = 0; mi < 4; ++mi)
#pragma unroll
                for (int ni = 0; ni < 4; ++ni)
                    acc[mi][ni] = __builtin_amdgcn_mfma_f32_16x16x32_bf16(a[mi], b[ni], acc[mi][ni], 0, 0, 0);
        }
        __syncthreads();
    }

#pragma unroll
    for (int mi = 0; mi < 4; ++mi) {
#pragma unroll
        for (int r = 0; r < 4; ++r) {
            int row = m0 + wm + mi * 16 + quad * 4 + r;
#pragma unroll
            for (int ni = 0; ni < 4; ++ni) {
                int col = n0 + wn + ni * 16 + l16;
                size_t idx = (size_t)row * IN + col;
                Weff[idx] = (__bf16)(acc[mi][ni][r] + W[idx]);
            }
        }
    }
}

// ---------- kernel 3: out[m][n] = sum_k X[m][k]*Weff[n][k] + bias[n] ----------
// 256x256 tile, BK=32, 8 waves (2Mx4N), 512 threads, 4-deep LDS ring (128 KiB).
// Deep-pipelined schedule (T3+T4+T5): per K-tile, 2 phases of
// {8/4 ds_read_b128 | 2 global_load_lds | barrier | setprio(1) 16xMFMA setprio(0) | barrier};
// ONE counted s_waitcnt vmcnt(8) per K-tile (never 0 in main loop) -> stage loads
// for tiles t+2/t+3 stay in flight across barriers. Invariant: vmcnt(8) at end of
// tile t leaves exactly {X(t+2),W(t+2),X(t+3),W(t+3)} (4 stages x 2 loads/thread)
// outstanding => tile t+1 fully resident. Epilogue drains 8 -> 4 -> 0.
// LDS swizzle: slot = chunk ^ ((row>>1)&3) at 16B granularity (4 chunks/row of
// 64B). Stage dst stays linear (gload_lds requirement); SOURCE chunk pre-swizzled.
// Read conflicts: within each 16-lane group, 8 distinct (parity,slot) positions
// x 4 banks = 32 banks, 2 lanes each -> 2-way = free (m136).
// C/D layout as verified: col = lane&15, row = quad*4 + reg.

#define LD_A(BUF, mi) (*(const bf16x8*)&sX[BUF][abase + (mi) * 512])
#define LD_B(BUF, ni) (*(const bf16x8*)&sW[BUF][bbase + (ni) * 512])
#define BARR() __builtin_amdgcn_s_barrier()
#define VM(N)  asm volatile("s_waitcnt vmcnt(" #N ")")

#define STG_X(BUF, P) do { \
    GLOAD_LDS16((P),          &sX[BUF][tid * 8]); \
    GLOAD_LDS16((P) + 524288, &sX[BUF][4096 + tid * 8]); \
} while (0)
#define STG_W(BUF, P) do { \
    GLOAD_LDS16((P),          &sW[BUF][tid * 8]); \
    GLOAD_LDS16((P) + 524288, &sW[BUF][4096 + tid * 8]); \
} while (0)

#define MROW(mi, A) \
    acc[mi][0] = __builtin_amdgcn_mfma_f32_16x16x32_bf16(A, b0, acc[mi][0], 0, 0, 0); \
    acc[mi][1] = __builtin_amdgcn_mfma_f32_16x16x32_bf16(A, b1, acc[mi][1], 0, 0, 0); \
    acc[mi][2] = __builtin_amdgcn_mfma_f32_16x16x32_bf16(A, b2, acc[mi][2], 0, 0, 0); \
    acc[mi][3] = __builtin_amdgcn_mfma_f32_16x16x32_bf16(A, b3, acc[mi][3], 0, 0, 0);

#define TILE(BUF, S1, S2, VMS) \
    { \
        bf16x8 a0 = LD_A(BUF, 0), a1 = LD_A(BUF, 1), a2 = LD_A(BUF, 2), a3 = LD_A(BUF, 3); \
        b0 = LD_B(BUF, 0); b1 = LD_B(BUF, 1); b2 = LD_B(BUF, 2); b3 = LD_B(BUF, 3); \
        S1; \
        BARR(); \
        __builtin_amdgcn_s_setprio(1); \
        MROW(0, a0) MROW(1, a1) MROW(2, a2) MROW(3, a3) \
        __builtin_amdgcn_s_setprio(0); \
        BARR(); \
        a0 = LD_A(BUF, 4); a1 = LD_A(BUF, 5); a2 = LD_A(BUF, 6); a3 = LD_A(BUF, 7); \
        S2; \
        BARR(); \
        __builtin_amdgcn_s_setprio(1); \
        MROW(4, a0) MROW(5, a1) MROW(6, a2) MROW(7, a3) \
        __builtin_amdgcn_s_setprio(0); \
        VMS; \
        BARR(); \
        __builtin_amdgcn_sched_barrier(0); \
    }

__global__ __launch_bounds__(512, 2) void main_gemm(
    const __bf16* __restrict__ X,     // [8192, 4096] bf16
    const __bf16* __restrict__ Wf,    // [4096, 4096] bf16
    const float*  __restrict__ bias,  // [4096]
    float* __restrict__ out)          // [8192, 4096] fp32
{
    constexpr int K = IN;     // 4096
    constexpr int N = OUT;    // 4096
    __shared__ __bf16 sX[4][8192];    // 4 bufs x 256 rows x 32 k  (64 KiB)
    __shared__ __bf16 sW[4][8192];    // 4 bufs x 256 rows x 32 k  (64 KiB)

    const int tid  = threadIdx.x;
    const int lane = tid & 63;
    const int quad = lane >> 4;
    const int l16  = lane & 15;
    const int wave = tid >> 6;
    const int wmb  = (wave >> 2) * 128;   // wave's M offset within tile
    const int wnb  = (wave & 3) * 64;     // wave's N offset within tile

    const int m0 = blockIdx.y * 256;
    const int n0 = blockIdx.x * 256;

    // fragment read addressing (slot is thread-constant: single K-step per tile)
    const int slot  = quad ^ ((l16 >> 1) & 3);
    const int abase = (wmb + l16) * 32 + slot * 8;
    const int bbase = (wnb + l16) * 32 + slot * 8;

    // stage addressing: linear LDS dst, pre-swizzled global source chunk
    const int row0 = tid >> 2;                          // 0..127 (j=1 adds 128)
    const int ch0  = (tid & 3) ^ ((row0 >> 1) & 3);     // same for both j halves
    const __bf16* xsrc = X  + (size_t)(m0 + row0) * K + ch0 * 8;
    const __bf16* wsrc = Wf + (size_t)(n0 + row0) * K + ch0 * 8;

    f32x4 acc[8][4] = {};
    bf16x8 b0, b1, b2, b3;

    // prologue: stage tiles 0,1,2 (12 loads/thread); wait tile 0 (leave 8 in flight)
    STG_X(0, xsrc);      STG_W(0, wsrc);
    STG_X(1, xsrc + 32); STG_W(1, wsrc + 32);
    STG_X(2, xsrc + 64); STG_W(2, wsrc + 64);
    VM(8);
    BARR();

    const __bf16* xs = xsrc + 96;   // next stage = tile 3
    const __bf16* ws = wsrc + 96;

    // main loop: tiles 0..123 (31 iters x 4), stage lookahead = 3 tiles
#pragma unroll 1
    for (int it = 0; it < 31; ++it) {
        TILE(0, STG_X(3, xs),      STG_W(3, ws),      VM(8))
        TILE(1, STG_X(0, xs + 32), STG_W(0, ws + 32), VM(8))
        TILE(2, STG_X(1, xs + 64), STG_W(1, ws + 64), VM(8))
        TILE(3, STG_X(2, xs + 96), STG_W(2, ws + 96), VM(8))
        xs += 128; ws += 128;
    }

    // epilogue: tiles 124..127; tile 124 stages tile 127; drain 8 -> 4 -> 0
    TILE(0, STG_X(3, xs), STG_W(3, ws), VM(8))
    TILE(1, (void)0,      (void)0,      VM(4))
    TILE(2, (void)0,      (void)0,      VM(0))
    TILE(3, (void)0,      (void)0,      (void)0)

    float bv[4];
#pragma unroll
    for (int ni = 0; ni < 4; ++ni)
        bv[ni] = bias[n0 + wnb + ni * 16 + l16];

#pragma unroll
    for (int mi = 0; mi < 8; ++mi) {
#pragma unroll
        for (int r = 0; r < 4; ++r) {
            int row = m0 + wmb + mi * 16 + quad * 4 + r;
#pragma unroll
            for (int ni = 0; ni < 4; ++ni) {
                int col = n0 + wnb + ni * 16 + l16;
                out[(size_t)row * N + col] = acc[mi][ni][r] + bv[ni];
            }
        }
    }
}

#undef TILE
#undef MROW
#undef STG_X
#undef STG_W
#undef LD_A
#undef LD_B
#undef BARR
#undef VM

// ---------- launch ----------
extern "C" void kernel_launch(void* const* d_in, const int* in_sizes, int n_in,
                              void* d_out, int out_size, void* d_ws, size_t ws_size,
                              hipStream_t stream) {
    const float* x  = (const float*)d_in[0];   // [8192, 4096]
    const float* W  = (const float*)d_in[1];   // [4096, 4096]
    const float* A  = (const float*)d_in[2];   // [256, 4096]
    const float* Bm = (const float*)d_in[3];   // [4096, 256]
    const float* d  = (const float*)d_in[4];   // [256]
    const float* b  = (const float*)d_in[5];   // [4096]
    float* out = (float*)d_out;

    // workspace layout
    char* ws = (char*)d_ws;
    __bf16* x_bf   = (__bf16*)(ws);                                  // 67,108,864 B
    __bf16* weff   = (__bf16*)(ws + (size_t)67108864);               // 33,554,432 B
    __bf16* b_bf   = (__bf16*)(ws + (size_t)67108864 + 33554432);    //  2,097,152 B
    __bf16* adt_bf = (__bf16*)(ws + (size_t)67108864 + 33554432 + 2097152); // 2,097,152 B

    // 1) prep: cast B (512 blocks) + AdT transpose (256 blocks)
    prep<<<768, 256, 0, stream>>>(Bm, b_bf, A, d, adt_bf);
    // 2) fused: Weff GEMM (1024 blocks) + cast x (16384 blocks)
    weff_cast<<<1024 + 16384, 256, 0, stream>>>(b_bf, adt_bf, W, weff, x, x_bf);
    // 3) out = x_bf @ Weff^T + b   (256^2 tile, deep-pipelined)
    main_gemm<<<dim3(OUT / 256, M_ROWS / 256), 512, 0, stream>>>(x_bf, weff, b, out);
}

// Round 2
// 532.136 us; speedup vs baseline: 1.0002x; 1.0002x over previous
//
#include <hip/hip_runtime.h>
#include <hip/hip_bf16.h>
#include <cstdint>

// ---------- types ----------
typedef __bf16 bf16x8 __attribute__((ext_vector_type(8)));
typedef float  f32x4  __attribute__((ext_vector_type(4)));

typedef __attribute__((address_space(3))) void lds_void;
typedef const __attribute__((address_space(1))) void gbl_cvoid;

#define GLOAD_LDS16(g, l) \
    __builtin_amdgcn_global_load_lds((gbl_cvoid*)(g), (lds_void*)(l), 16, 0, 0)

// Problem constants
static constexpr int IN   = 4096;
static constexpr int OUT  = 4096;
static constexpr int RANK = 256;
static constexpr int M_ROWS = 4 * 2048;  // B*S = 8192

// ---------- device helpers ----------
__device__ __forceinline__ void cast8(const float* __restrict__ in,
                                      __bf16* __restrict__ out, int t) {
    const float4* p = (const float4*)in + (size_t)t * 2;
    float4 v0 = p[0], v1 = p[1];
    bf16x8 o;
    o[0] = (__bf16)v0.x; o[1] = (__bf16)v0.y; o[2] = (__bf16)v0.z; o[3] = (__bf16)v0.w;
    o[4] = (__bf16)v1.x; o[5] = (__bf16)v1.y; o[6] = (__bf16)v1.z; o[7] = (__bf16)v1.w;
    ((bf16x8*)out)[t] = o;
}

// ---------- kernel 1: prep = cast B (blocks 0..511) + make AdT (blocks 512..767) ----
__global__ __launch_bounds__(256) void prep(
    const float* __restrict__ Bm, __bf16* __restrict__ Bbf,
    const float* __restrict__ A,  const float* __restrict__ d,
    __bf16* __restrict__ AdT)
{
    __shared__ float tile[64][65];
    const int blk = blockIdx.x;
    const int t   = threadIdx.x;

    if (blk < 512) {                     // cast B: 1,048,576 elems / 8
        cast8(Bm, Bbf, blk * 256 + t);
        return;
    }
    const int ab = blk - 512;            // 0..255
    const int i0 = (ab & 63) * 64;
    const int r0 = (ab >> 6) * 64;
    const int cl = t & 63;
    const int rw = t >> 6;

#pragma unroll
    for (int it = 0; it < 16; ++it) {
        int rl = it * 4 + rw;
        tile[rl][cl] = A[(size_t)(r0 + rl) * IN + i0 + cl];
    }
    __syncthreads();
    float dv = d[r0 + cl];
#pragma unroll
    for (int it = 0; it < 16; ++it) {
        int il = it * 4 + rw;
        AdT[(size_t)(i0 + il) * RANK + r0 + cl] = (__bf16)(tile[cl][il] * dv);
    }
}

// ---------- kernel 2: fused Weff-GEMM (blocks 0..1023) + cast x (rest) ----------
// Weff[o][i] = bf16( W[o][i] + sum_r Bw[o][r]*AdT[i][r] )  (128x128 tile, verified)
__global__ __launch_bounds__(256) void weff_cast(
    const __bf16* __restrict__ Bw,   // [OUT, RANK] bf16
    const __bf16* __restrict__ AdT,  // [IN,  RANK] bf16
    const float*  __restrict__ W,    // [OUT, IN] fp32
    __bf16* __restrict__ Weff,       // [OUT, IN] bf16
    const float*  __restrict__ x,    // [8192, 4096] fp32
    __bf16* __restrict__ x_bf)       // [8192, 4096] bf16
{
    __shared__ __bf16 sA[128 * 64];
    __shared__ __bf16 sB[128 * 64];

    const int blk = blockIdx.x;
    const int t   = threadIdx.x;

    if (blk >= 1024) {                   // cast x: 33,554,432 elems / 8
        cast8(x, x_bf, (blk - 1024) * 256 + t);
        return;
    }

    constexpr int K = RANK;   // 256
    const int wave = t >> 6;
    const int lane = t & 63;
    const int quad = lane >> 4;
    const int l16  = lane & 15;
    const int m0 = (blk >> 5) * 128;   // o
    const int n0 = (blk & 31) * 128;   // i
    const int wm = (wave >> 1) * 64;
    const int wn = (wave & 1) * 64;
    const int xr = l16 & 7;

    f32x4 acc[4][4] = {};

    for (int kt = 0; kt < K; kt += 64) {
#pragma unroll
        for (int j = 0; j < 4; ++j) {
            int ci  = j * 256 + t;
            int row = ci >> 3;
            int kc  = (ci & 7) ^ (row & 7);
            GLOAD_LDS16(Bw  + (size_t)(m0 + row) * K + kt + kc * 8, sA + ci * 8);
        }
#pragma unroll
        for (int j = 0; j < 4; ++j) {
            int ci  = j * 256 + t;
            int row = ci >> 3;
            int kc  = (ci & 7) ^ (row & 7);
            GLOAD_LDS16(AdT + (size_t)(n0 + row) * K + kt + kc * 8, sB + ci * 8);
        }
        __syncthreads();

#pragma unroll
        for (int kk = 0; kk < 64; kk += 32) {
            const int kb = kk >> 3;
            bf16x8 a[4], b[4];
#pragma unroll
            for (int mi = 0; mi < 4; ++mi)
                a[mi] = *(const bf16x8*)(sA + (wm + mi * 16 + l16) * 64 + (((kb + quad) ^ xr) << 3));
#pragma unroll
            for (int ni = 0; ni < 4; ++ni)
                b[ni] = *(const bf16x8*)(sB + (wn + ni * 16 + l16) * 64 + (((kb + quad) ^ xr) << 3));
#pragma unroll
            for (int mi = 0; mi < 4; ++mi)
#pragma unroll
                for (int ni = 0; ni < 4; ++ni)
                    acc[mi][ni] = __builtin_amdgcn_mfma_f32_16x16x32_bf16(a[mi], b[ni], acc[mi][ni], 0, 0, 0);
        }
        __syncthreads();
    }

#pragma unroll
    for (int mi = 0; mi < 4; ++mi) {
#pragma unroll
        for (int r = 0; r < 4; ++r) {
            int row = m0 + wm + mi * 16 + quad * 4 + r;
#pragma unroll
            for (int ni = 0; ni < 4; ++ni) {
                int col = n0 + wn + ni * 16 + l16;
                size_t idx = (size_t)row * IN + col;
                Weff[idx] = (__bf16)(acc[mi][ni][r] + W[idx]);
            }
        }
    }
}

// ---------- kernel 3: out[m][n] = sum_k X[m][k]*Weff[n][k] + bias[n] ----------
// 256x256 tile, BK=32, 8 waves (2Mx4N), 512 threads, 4-deep LDS ring (128 KiB).
// Deep-pipelined schedule (T3+T4+T5), verified R1 (46% MfmaUtil, 0 bank conflicts).
// R2 changes (mapping only; sync structure byte-identical):
//  * Persistent blocks: grid 256 = 1 block/CU; each block computes TWO output
//    tiles (m_base, n) then (m_base+16, n) -> same W panel, no 2nd dispatch round.
//    tp-loop prologue uses one VM(0) bridge: previous tile's C-stores + new
//    prologue stage loads drain in a single overlapped wait; the steady-state
//    VM(8) invariant re-establishes by TILE(2) (0 outstanding at loop entry:
//    T0 stage->4, noop; T1 stage->8, noop; T2 stage->12, VM(8) retires t3 ✓).
//  * XCD-aware decode: XCD c (= blk&7, HW round-robin) gets n-columns {2c,2c+1}
//    -> per-XCD W working set = 2x2MB = 4MB = L2 size; n-pair blocks (i, i^1)
//    share the same X panel -> 2-way L2 reuse on X. (T1; FETCH_SIZE was 3x ideal.)

#define LD_A(BUF, mi) (*(const bf16x8*)&sX[BUF][abase + (mi) * 512])
#define LD_B(BUF, ni) (*(const bf16x8*)&sW[BUF][bbase + (ni) * 512])
#define BARR() __builtin_amdgcn_s_barrier()
#define VM(N)  asm volatile("s_waitcnt vmcnt(" #N ")")

#define STG_X(BUF, P) do { \
    GLOAD_LDS16((P),          &sX[BUF][tid * 8]); \
    GLOAD_LDS16((P) + 524288, &sX[BUF][4096 + tid * 8]); \
} while (0)
#define STG_W(BUF, P) do { \
    GLOAD_LDS16((P),          &sW[BUF][tid * 8]); \
    GLOAD_LDS16((P) + 524288, &sW[BUF][4096 + tid * 8]); \
} while (0)

#define MROW(mi, A) \
    acc[mi][0] = __builtin_amdgcn_mfma_f32_16x16x32_bf16(A, b0, acc[mi][0], 0, 0, 0); \
    acc[mi][1] = __builtin_amdgcn_mfma_f32_16x16x32_bf16(A, b1, acc[mi][1], 0, 0, 0); \
    acc[mi][2] = __builtin_amdgcn_mfma_f32_16x16x32_bf16(A, b2, acc[mi][2], 0, 0, 0); \
    acc[mi][3] = __builtin_amdgcn_mfma_f32_16x16x32_bf16(A, b3, acc[mi][3], 0, 0, 0);

#define TILE(BUF, S1, S2, VMS) \
    { \
        bf16x8 a0 = LD_A(BUF, 0), a1 = LD_A(BUF, 1), a2 = LD_A(BUF, 2), a3 = LD_A(BUF, 3); \
        b0 = LD_B(BUF, 0); b1 = LD_B(BUF, 1); b2 = LD_B(BUF, 2); b3 = LD_B(BUF, 3); \
        S1; \
        BARR(); \
        __builtin_amdgcn_s_setprio(1); \
        MROW(0, a0) MROW(1, a1) MROW(2, a2) MROW(3, a3) \
        __builtin_amdgcn_s_setprio(0); \
        BARR(); \
        a0 = LD_A(BUF, 4); a1 = LD_A(BUF, 5); a2 = LD_A(BUF, 6); a3 = LD_A(BUF, 7); \
        S2; \
        BARR(); \
        __builtin_amdgcn_s_setprio(1); \
        MROW(4, a0) MROW(5, a1) MROW(6, a2) MROW(7, a3) \
        __builtin_amdgcn_s_setprio(0); \
        VMS; \
        BARR(); \
        __builtin_amdgcn_sched_barrier(0); \
    }

__global__ __launch_bounds__(512, 2) void main_gemm(
    const __bf16* __restrict__ X,     // [8192, 4096] bf16
    const __bf16* __restrict__ Wf,    // [4096, 4096] bf16
    const float*  __restrict__ bias,  // [4096]
    float* __restrict__ out)          // [8192, 4096] fp32
{
    constexpr int K = IN;     // 4096
    constexpr int N = OUT;    // 4096
    __shared__ __bf16 sX[4][8192];    // 4 bufs x 256 rows x 32 k  (64 KiB)
    __shared__ __bf16 sW[4][8192];    // 4 bufs x 256 rows x 32 k  (64 KiB)

    const int tid  = threadIdx.x;
    const int lane = tid & 63;
    const int quad = lane >> 4;
    const int l16  = lane & 15;
    const int wave = tid >> 6;
    const int wmb  = (wave >> 2) * 128;   // wave's M offset within tile
    const int wnb  = (wave & 3) * 64;     // wave's N offset within tile

    // XCD-aware persistent-block decode (bijective: blk = c | (i<<3))
    const int blk    = blockIdx.x;        // 0..255, HW: XCD = blk & 7
    const int c      = blk & 7;
    const int i      = blk >> 3;          // 0..31 (one per CU in the XCD)
    const int n0     = (c * 2 + (i & 1)) * 256;   // XCD c owns n-cols {2c, 2c+1}
    const int m_base = (i >> 1) * 256;            // tp adds 16*256

    // fragment read addressing (slot is thread-constant: single K-step per tile)
    const int slot  = quad ^ ((l16 >> 1) & 3);
    const int abase = (wmb + l16) * 32 + slot * 8;
    const int bbase = (wnb + l16) * 32 + slot * 8;

    // stage addressing: linear LDS dst, pre-swizzled global source chunk
    const int row0 = tid >> 2;                          // 0..127 (j=1 adds 128)
    const int ch0  = (tid & 3) ^ ((row0 >> 1) & 3);     // same for both j halves
    const __bf16* wsrc = Wf + (size_t)(n0 + row0) * K + ch0 * 8;

    float bv[4];
#pragma unroll
    for (int ni = 0; ni < 4; ++ni)
        bv[ni] = bias[n0 + wnb + ni * 16 + l16];

    bf16x8 b0, b1, b2, b3;

#pragma unroll 1
    for (int tp = 0; tp < 2; ++tp) {
        const int m0 = m_base + tp * 4096;
        const __bf16* xsrc = X + (size_t)(m0 + row0) * K + ch0 * 8;

        f32x4 acc[8][4] = {};

        // prologue: stage tiles 0,1,2; VM(0) bridge drains (prev-tp stores +)
        // these loads in one overlapped wait; 0 outstanding at loop entry.
        STG_X(0, xsrc);      STG_W(0, wsrc);
        STG_X(1, xsrc + 32); STG_W(1, wsrc + 32);
        STG_X(2, xsrc + 64); STG_W(2, wsrc + 64);
        VM(0);
        BARR();

        const __bf16* xs = xsrc + 96;   // next stage = tile 3
        const __bf16* ws = wsrc + 96;

        // main loop: tiles 0..123 (31 iters x 4), stage lookahead = 3 tiles
#pragma unroll 1
        for (int it = 0; it < 31; ++it) {
            TILE(0, STG_X(3, xs),      STG_W(3, ws),      VM(8))
            TILE(1, STG_X(0, xs + 32), STG_W(0, ws + 32), VM(8))
            TILE(2, STG_X(1, xs + 64), STG_W(1, ws + 64), VM(8))
            TILE(3, STG_X(2, xs + 96), STG_W(2, ws + 96), VM(8))
            xs += 128; ws += 128;
        }

        // epilogue: tiles 124..127; tile 124 stages tile 127; drain 8 -> 4 -> 0
        TILE(0, STG_X(3, xs), STG_W(3, ws), VM(8))
        TILE(1, (void)0,      (void)0,      VM(4))
        TILE(2, (void)0,      (void)0,      VM(0))
        TILE(3, (void)0,      (void)0,      (void)0)

        // C-write (stores left in flight; next tp's VM(0) overlaps their drain)
#pragma unroll
        for (int mi = 0; mi < 8; ++mi) {
#pragma unroll
            for (int r = 0; r < 4; ++r) {
                int row = m0 + wmb + mi * 16 + quad * 4 + r;
#pragma unroll
                for (int ni = 0; ni < 4; ++ni) {
                    int col = n0 + wnb + ni * 16 + l16;
                    out[(size_t)row * N + col] = acc[mi][ni][r] + bv[ni];
                }
            }
        }
    }
}

#undef TILE
#undef MROW
#undef STG_X
#undef STG_W
#undef LD_A
#undef LD_B
#undef BARR
#undef VM

// ---------- launch ----------
extern "C" void kernel_launch(void* const* d_in, const int* in_sizes, int n_in,
                              void* d_out, int out_size, void* d_ws, size_t ws_size,
                              hipStream_t stream) {
    const float* x  = (const float*)d_in[0];   // [8192, 4096]
    const float* W  = (const float*)d_in[1];   // [4096, 4096]
    const float* A  = (const float*)d_in[2];   // [256, 4096]
    const float* Bm = (const float*)d_in[3];   // [4096, 256]
    const float* d  = (const float*)d_in[4];   // [256]
    const float* b  = (const float*)d_in[5];   // [4096]
    float* out = (float*)d_out;

    // workspace layout
    char* ws = (char*)d_ws;
    __bf16* x_bf   = (__bf16*)(ws);                                  // 67,108,864 B
    __bf16* weff   = (__bf16*)(ws + (size_t)67108864);               // 33,554,432 B
    __bf16* b_bf   = (__bf16*)(ws + (size_t)67108864 + 33554432);    //  2,097,152 B
    __bf16* adt_bf = (__bf16*)(ws + (size_t)67108864 + 33554432 + 2097152); // 2,097,152 B

    // 1) prep: cast B (512 blocks) + AdT transpose (256 blocks)
    prep<<<768, 256, 0, stream>>>(Bm, b_bf, A, d, adt_bf);
    // 2) fused: Weff GEMM (1024 blocks) + cast x (16384 blocks)
    weff_cast<<<1024 + 16384, 256, 0, stream>>>(b_bf, adt_bf, W, weff, x, x_bf);
    // 3) out = x_bf @ Weff^T + b   (256^2 tile, persistent 2-tile blocks, XCD-aware)
    main_gemm<<<256, 512, 0, stream>>>(x_bf, weff, b, out);
}